// Round 7
// baseline (224.844 us; speedup 1.0000x reference)
//
#include <hip/hip_runtime.h>

#define HH 512
#define WW 512
#define HW (512*512)
#define NB 8
#define ND 16
#define TW 64            // tile width (output)
#define TH 32            // tile height (output)
#define VR 42            // v-sum rows = TH+10
#define PT 86            // LDS pitch (EVEN -> 8B alignment for all even-col accesses)

__device__ __forceinline__ int reflect(int v) {
    if (v < 0) v = -v;
    if (v >= HH) v = 2*HH - 2 - v;
    return v;
}

// ---------------- Prepass: {mean_I, 1/(var_I+eps)} interleaved float2, per image -------
__global__ __launch_bounds__(256) void img_stats(const float* __restrict__ img,
                                                 float2* __restrict__ miv) {
    const int EE = 42, Q = 43, PH = 33;
    __shared__ float sI[EE*Q], sI2[EE*Q];
    __shared__ float hI[EE*PH], hI2[EE*PH];

    int blk  = blockIdx.x;
    int tile = blk & 255;
    int b    = blk >> 8;
    int ty0  = (tile >> 4) * 32;
    int tx0  = (tile & 15) * 32;
    const float* ib = img + (size_t)b*HW;
    const float inv121 = 1.0f/121.0f;

    for (int i = threadIdx.x; i < EE*EE; i += 256) {
        int y = i / EE, x = i - y*EE;
        int gy = reflect(ty0 - 5 + y);
        int gx = reflect(tx0 - 5 + x);
        float v = ib[gy*WW + gx];
        sI [y*Q + x] = v;
        sI2[y*Q + x] = v*v;
    }
    __syncthreads();
    if (threadIdx.x < 168) {
        int t = threadIdx.x;
        int arr = t / 84, r2 = t - arr*84;
        int seg = r2 / 42, row = r2 - seg*42;
        const float* sr = (arr ? sI2 : sI) + row*Q;
        float* dr = (arr ? hI2 : hI) + row*PH;
        int x0 = seg*16;
        float s = 0.f;
        #pragma unroll
        for (int j = 0; j < 10; ++j) s += sr[x0+j];
        #pragma unroll
        for (int x = 0; x < 16; ++x) {
            s += sr[x0+x+10];
            dr[x0+x] = s;
            s -= sr[x0+x];
        }
    }
    __syncthreads();
    {
        int t = threadIdx.x;
        int arr = t >> 7, r2 = t & 127;
        int seg = r2 >> 5, col = r2 & 31;
        const float* src = arr ? hI2 : hI;
        float* dst = arr ? sI2 : sI;
        int y0 = seg*8;
        float s = 0.f;
        #pragma unroll
        for (int j = 0; j < 10; ++j) s += src[(y0+j)*PH+col];
        #pragma unroll
        for (int k = 0; k < 8; ++k) {
            int y = y0 + k;
            s += src[(y+10)*PH+col];
            dst[y*Q+col] = s;
            s -= src[y*PH+col];
        }
    }
    __syncthreads();
    for (int i = threadIdx.x; i < 32*32; i += 256) {
        int y = i >> 5, x = i & 31;
        float mI  = sI [y*Q+x]*inv121;
        float mII = sI2[y*Q+x]*inv121;
        float var = mII - mI*mI;
        int gy = ty0 + y, gx = tx0 + x;
        float2 o; o.x = mI; o.y = 1.0f / (var + 1e-8f);
        miv[(size_t)b*HW + gy*WW + gx] = o;
    }
}

// ---------------- Main fused kernel: one (b,d) channel, one 64x32 tile -----------------
// Vertical-first, all LDS traffic as float2 (b64). LDS: hF/hP [42][86] = 28.9 KB.
// Logical->physical maps (even boundaries keep float2 pairs intact):
//   cols after B : slot(c) = c + 10*(c>=38)    (c in 0..73)
//   rows after C : prow(y) = y + 10*(y>=16)    (y in 0..31)
//   cols after D : wcol(x) = x + 20*(x>=32)    (x in 0..63)
__global__ __launch_bounds__(256) void guided_main(const float* __restrict__ feat,
                                                   const float* __restrict__ img,
                                                   const float2* __restrict__ miv,
                                                   float* __restrict__ out) {
    __shared__ __align__(16) float hF[VR*PT];
    __shared__ __align__(16) float hP[VR*PT];

    int blk  = blockIdx.x;
    int tile = blk & 127;        // 8 col-tiles x 16 row-tiles
    int bd   = blk >> 7;
    int b    = bd >> 4;
    int ty0  = (tile >> 3) * TH;
    int tx0  = (tile & 7)  * TW;

    const float inv121 = 1.0f/121.0f;
    const float* fb   = feat + (size_t)bd*HW;
    const float* ib   = img  + (size_t)b*HW;
    const float2* mivb = miv + (size_t)b*HW;
    const int t = threadIdx.x;

    // ---- Phase A: vertical raw 11-sums of feat & img*feat; column-pair threads ----
    // 42 pairs x 6 row-segs (7 outputs each) = 252 threads; float2 global loads.
    if (t < 252) {
        int seg = t / 42, c2 = t - seg*42;
        int col0 = 2*c2;
        int gx0 = tx0 - 10 + col0;
        bool edge = (gx0 < 0) || (gx0 > WW-2);
        int rg0 = reflect(gx0), rg1 = reflect(gx0+1);
        int vr0 = seg*7;
        float2 rf[11], rp[11];
        float sfx=0.f, sfy=0.f, spx=0.f, spy=0.f;
        #pragma unroll
        for (int j = 0; j < 10; ++j) {
            int gy = reflect(ty0 - 10 + vr0 + j);
            const float* fr = fb + gy*WW;
            const float* ir = ib + gy*WW;
            float2 f2, i2;
            if (edge) { f2.x = fr[rg0]; f2.y = fr[rg1]; i2.x = ir[rg0]; i2.y = ir[rg1]; }
            else      { f2 = *(const float2*)(fr + gx0); i2 = *(const float2*)(ir + gx0); }
            float2 p2; p2.x = f2.x*i2.x; p2.y = f2.y*i2.y;
            rf[j] = f2; rp[j] = p2;
            sfx += f2.x; sfy += f2.y; spx += p2.x; spy += p2.y;
        }
        #pragma unroll
        for (int k = 0; k < 7; ++k) {
            int vr = vr0 + k;
            int gy = reflect(ty0 + vr);
            const float* fr = fb + gy*WW;
            const float* ir = ib + gy*WW;
            float2 f2, i2;
            if (edge) { f2.x = fr[rg0]; f2.y = fr[rg1]; i2.x = ir[rg0]; i2.y = ir[rg1]; }
            else      { f2 = *(const float2*)(fr + gx0); i2 = *(const float2*)(ir + gx0); }
            float2 p2; p2.x = f2.x*i2.x; p2.y = f2.y*i2.y;
            sfx += f2.x; sfy += f2.y; spx += p2.x; spy += p2.y;
            float2 oF; oF.x = sfx; oF.y = sfy;
            float2 oP; oP.x = spx; oP.y = spy;
            *(float2*)(&hF[vr*PT + col0]) = oF;
            *(float2*)(&hP[vr*PT + col0]) = oP;
            sfx -= rf[k%11].x; sfy -= rf[k%11].y;
            spx -= rp[k%11].x; spy -= rp[k%11].y;
            rf[(k+10)%11] = f2; rp[(k+10)%11] = p2;
        }
    }
    __syncthreads();

    // ---- Phase B: horizontal 11-sums -> mp/cip (x inv121) in place at col-slots ----
    // 42 rows x 2 segs x 2 arrays = 168 threads; pair outputs via 10-sum trick.
    // seg0: reads raw 0..47, writes 0..37. seg1: reads raw 38..83, writes 48..83
    // (same-addr read-then-write within thread; cross-seg disjoint).
    if (t < 168) {
        int arr = t & 1;
        int j2  = t >> 1;                    // 0..83
        int seg = (j2 >= 42) ? 1 : 0;
        int vr  = j2 - seg*42;
        int xb = seg ? 38 : 0;
        int nout = seg ? 18 : 19;            // pairs
        float* rA = (arr ? hP : hF) + vr*PT;
        float2 ring[5];
        float T = 0.f;
        #pragma unroll
        for (int j = 0; j < 5; ++j) {
            float2 v = *(float2*)(rA + xb + 2*j);
            ring[j] = v; T += v.x + v.y;
        }
        #pragma unroll
        for (int k2 = 0; k2 < 19; ++k2) {
            if (k2 < nout) {
                int hc = xb + 2*k2;
                float2 p = *(float2*)(rA + hc + 10);
                float2 q = ring[k2 % 5];
                float O0 = T + p.x;
                float O1 = O0 + p.y - q.x;
                T = O1 - q.y;
                ring[k2 % 5] = p;
                float2 o; o.x = O0*inv121; o.y = O1*inv121;
                *(float2*)(rA + hc + 10*seg) = o;
            }
        }
    }
    __syncthreads();

    // ---- Phase B2: a,b elementwise on pairs; aligned float2 miv loads; in place ----
    for (int i = t; i < VR*37; i += 256) {
        int y = i / 37, c2 = i - y*37;
        int x0 = 2*c2;
        int slot = x0 + ((x0 >= 38) ? 10 : 0);
        float* pF = &hF[y*PT + slot];
        float* pP = &hP[y*PT + slot];
        float2 mp2  = *(float2*)pF;
        float2 cip2 = *(float2*)pP;
        int gy = reflect(ty0 - 5 + y);
        const float2* mrow = mivb + gy*WW;
        int gx0 = tx0 - 5 + x0;
        float2 g0 = mrow[reflect(gx0)];
        float2 g1 = mrow[reflect(gx0+1)];
        float a0 = (cip2.x - g0.x*mp2.x) * g0.y;
        float b0 = mp2.x - a0*g0.x;
        float a1 = (cip2.y - g1.x*mp2.y) * g1.y;
        float b1 = mp2.y - a1*g1.x;
        float2 oa; oa.x = a0; oa.y = a1;
        float2 ob2; ob2.x = b0; ob2.y = b1;
        *(float2*)pF = oa;
        *(float2*)pP = ob2;
    }
    __syncthreads();

    // ---- Phase C: vertical 11-sums of a,b; column-pair threads; row-slot in place ----
    // 37 pairs x 2 row-segs x 2 arrays = 148 threads.
    // seg0: reads rows 0..25, writes rows 0..15. seg1: reads 16..41, writes 26..41.
    if (t < 148) {
        int arr = t & 1;
        int j2  = t >> 1;                    // 0..73
        int seg = (j2 >= 37) ? 1 : 0;
        int c2  = j2 - seg*37;
        int x0 = 2*c2;
        int slotc = x0 + ((x0 >= 38) ? 10 : 0);
        int y0 = seg*16;
        float* A = (arr ? hP : hF);
        float2 ring[11];
        float sx = 0.f, sy = 0.f;
        #pragma unroll
        for (int j = 0; j < 10; ++j) {
            float2 v = *(float2*)(A + (y0+j)*PT + slotc);
            ring[j] = v; sx += v.x; sy += v.y;
        }
        #pragma unroll
        for (int k = 0; k < 16; ++k) {
            int y = y0 + k;
            float2 v = *(float2*)(A + (y+10)*PT + slotc);
            sx += v.x; sy += v.y;
            int wrow = y + 10*seg;
            float2 o; o.x = sx; o.y = sy;
            *(float2*)(A + wrow*PT + slotc) = o;
            sx -= ring[k%11].x; sy -= ring[k%11].y;
            ring[(k+10)%11] = v;
        }
    }
    __syncthreads();

    // ---- Phase D: horizontal 11-sums of summed a,b; pair trick; in place ----
    // 32 rows x 2 arrays x 2 col-segs = 128 threads.
    // seg0: reads slots{0..37,48..51}, writes cols 0..31. seg1: reads {32..37,48..83},
    // writes 52..83 (same-addr read-then-write; cross-seg disjoint).
    if (t < 128) {
        int arr = t & 1;
        int r2  = t >> 1;                    // 0..63
        int seg = r2 >> 5, row = r2 & 31;
        int prow = row + ((row >= 16) ? 10 : 0);
        float* rA = (arr ? hP : hF) + prow*PT;
        int xb = seg*32;
        float2 ring[5];
        float T = 0.f;
        #pragma unroll
        for (int j = 0; j < 5; ++j) {
            int idx = xb + 2*j;
            int sl = idx + ((idx >= 38) ? 10 : 0);
            float2 v = *(float2*)(rA + sl);
            ring[j] = v; T += v.x + v.y;
        }
        #pragma unroll
        for (int k2 = 0; k2 < 16; ++k2) {
            int x = xb + 2*k2;
            int idx = x + 10;
            int sl = idx + ((idx >= 38) ? 10 : 0);
            float2 p = *(float2*)(rA + sl);
            float2 q = ring[k2 % 5];
            float O0 = T + p.x;
            float O1 = O0 + p.y - q.x;
            T = O1 - q.y;
            ring[k2 % 5] = p;
            int wcol = x + 20*seg;
            float2 o; o.x = O0; o.y = O1;
            *(float2*)(rA + wcol) = o;
        }
    }
    __syncthreads();

    // ---- Phase D2: combine + coalesced float2 store ----
    float* ob = out + (size_t)bd*HW;
    for (int i = t; i < TH*32; i += 256) {
        int y = i >> 5, c2 = i & 31;
        int x0 = 2*c2;
        int prow = y + ((y >= 16) ? 10 : 0);
        int wcol = (x0 < 32) ? x0 : x0 + 20;
        float2 ma2 = *(float2*)(&hF[prow*PT + wcol]);
        float2 mb2 = *(float2*)(&hP[prow*PT + wcol]);
        int gy = ty0 + y;
        float2 im2 = *(const float2*)(ib + gy*WW + tx0 + x0);
        float2 o;
        o.x = (ma2.x*im2.x + mb2.x)*inv121;
        o.y = (ma2.y*im2.y + mb2.y)*inv121;
        *(float2*)(ob + gy*WW + tx0 + x0) = o;
    }
}

extern "C" void kernel_launch(void* const* d_in, const int* in_sizes, int n_in,
                              void* d_out, int out_size, void* d_ws, size_t ws_size,
                              hipStream_t stream) {
    const float* feat = (const float*)d_in[0];
    const float* img  = (const float*)d_in[1];
    float* out  = (float*)d_out;
    float2* miv = (float2*)d_ws;             // NB*HW float2 = 16 MiB

    img_stats<<<NB*256, 256, 0, stream>>>(img, miv);
    guided_main<<<NB*ND*128, 256, 0, stream>>>(feat, img, miv, out);
}

// Round 8
// 153.313 us; speedup vs baseline: 1.4666x; 1.4666x over previous
//
#include <hip/hip_runtime.h>

#define HH 512
#define WW 512
#define HW (512*512)
#define NB 8
#define ND 16
#define TW 64            // tile width (output)
#define TH 32            // tile height (output)
#define VR 42            // v-sum rows = TH+10
#define PT 86            // LDS pitch (EVEN -> 8B alignment for all even-col accesses)

__device__ __forceinline__ int reflect(int v) {
    if (v < 0) v = -v;
    if (v >= HH) v = 2*HH - 2 - v;
    return v;
}

// ---------------- Prepass: {mean_I, 1/(var_I+eps)} interleaved float2, per image -------
__global__ __launch_bounds__(256) void img_stats(const float* __restrict__ img,
                                                 float2* __restrict__ miv) {
    const int EE = 42, Q = 43, PH = 33;
    __shared__ float sI[EE*Q], sI2[EE*Q];
    __shared__ float hI[EE*PH], hI2[EE*PH];

    int blk  = blockIdx.x;
    int tile = blk & 255;
    int b    = blk >> 8;
    int ty0  = (tile >> 4) * 32;
    int tx0  = (tile & 15) * 32;
    const float* ib = img + (size_t)b*HW;
    const float inv121 = 1.0f/121.0f;

    for (int i = threadIdx.x; i < EE*EE; i += 256) {
        int y = i / EE, x = i - y*EE;
        int gy = reflect(ty0 - 5 + y);
        int gx = reflect(tx0 - 5 + x);
        float v = ib[gy*WW + gx];
        sI [y*Q + x] = v;
        sI2[y*Q + x] = v*v;
    }
    __syncthreads();
    if (threadIdx.x < 168) {
        int t = threadIdx.x;
        int arr = t / 84, r2 = t - arr*84;
        int seg = r2 / 42, row = r2 - seg*42;
        const float* sr = (arr ? sI2 : sI) + row*Q;
        float* dr = (arr ? hI2 : hI) + row*PH;
        int x0 = seg*16;
        float s = 0.f;
        #pragma unroll
        for (int j = 0; j < 10; ++j) s += sr[x0+j];
        #pragma unroll
        for (int x = 0; x < 16; ++x) {
            s += sr[x0+x+10];
            dr[x0+x] = s;
            s -= sr[x0+x];
        }
    }
    __syncthreads();
    {
        int t = threadIdx.x;
        int arr = t >> 7, r2 = t & 127;
        int seg = r2 >> 5, col = r2 & 31;
        const float* src = arr ? hI2 : hI;
        float* dst = arr ? sI2 : sI;
        int y0 = seg*8;
        float s = 0.f;
        #pragma unroll
        for (int j = 0; j < 10; ++j) s += src[(y0+j)*PH+col];
        #pragma unroll
        for (int k = 0; k < 8; ++k) {
            int y = y0 + k;
            s += src[(y+10)*PH+col];
            dst[y*Q+col] = s;
            s -= src[y*PH+col];
        }
    }
    __syncthreads();
    for (int i = threadIdx.x; i < 32*32; i += 256) {
        int y = i >> 5, x = i & 31;
        float mI  = sI [y*Q+x]*inv121;
        float mII = sI2[y*Q+x]*inv121;
        float var = mII - mI*mI;
        int gy = ty0 + y, gx = tx0 + x;
        float2 o; o.x = mI; o.y = 1.0f / (var + 1e-8f);
        miv[(size_t)b*HW + gy*WW + gx] = o;
    }
}

// ---------------- Main fused kernel: one (b,d) channel, one 64x32 tile -----------------
// Vertical-first. Phase A scalar (ring regs stay small); phases B..D2 float2.
// LDS: hF/hP [42][86] = 28.9 KB.
// Logical->physical maps (even boundaries keep float2 pairs intact):
//   cols after B : slot(c) = c + 10*(c>=38)    (c in 0..73)
//   rows after C : prow(y) = y + 10*(y>=16)    (y in 0..31)
//   cols after D : wcol(x) = x + 20*(x>=32)    (x in 0..63)
__global__ __launch_bounds__(256) void guided_main(const float* __restrict__ feat,
                                                   const float* __restrict__ img,
                                                   const float2* __restrict__ miv,
                                                   float* __restrict__ out) {
    __shared__ __align__(16) float hF[VR*PT];
    __shared__ __align__(16) float hP[VR*PT];

    int blk  = blockIdx.x;
    int tile = blk & 127;        // 8 col-tiles x 16 row-tiles
    int bd   = blk >> 7;
    int b    = bd >> 4;
    int ty0  = (tile >> 3) * TH;
    int tx0  = (tile & 7)  * TW;

    const float inv121 = 1.0f/121.0f;
    const float* fb   = feat + (size_t)bd*HW;
    const float* ib   = img  + (size_t)b*HW;
    const float2* mivb = miv + (size_t)b*HW;
    const int t = threadIdx.x;

    // ---- Phase A: vertical raw 11-sums of feat & img*feat (scalar, coalesced) ----
    // 84 cols x 3 row-segs (14 outputs each) = 252 threads; lanes = consecutive columns.
    if (t < 252) {
        int seg = t / 84, col = t - seg*84;
        int gx = reflect(tx0 - 10 + col);
        const float* fcol = fb + gx;
        const float* icol = ib + gx;
        int vr0 = seg*14;
        float rf[11], rp[11];
        float sf = 0.f, sp = 0.f;
        #pragma unroll
        for (int j = 0; j < 10; ++j) {
            int gy = reflect(ty0 - 10 + vr0 + j);
            float f = fcol[gy*WW], im = icol[gy*WW];
            float p = f*im;
            rf[j] = f; rp[j] = p; sf += f; sp += p;
        }
        #pragma unroll
        for (int k = 0; k < 14; ++k) {
            int vr = vr0 + k;
            int gy = reflect(ty0 + vr);     // = ty0-10 + (vr+10)
            float f = fcol[gy*WW], im = icol[gy*WW];
            float p = f*im;
            sf += f; sp += p;
            hF[vr*PT + col] = sf;
            hP[vr*PT + col] = sp;
            sf -= rf[k%11]; sp -= rp[k%11];
            rf[(k+10)%11] = f; rp[(k+10)%11] = p;
        }
    }
    __syncthreads();

    // ---- Phase B: horizontal 11-sums -> mp/cip (x inv121) in place at col-slots ----
    // 42 rows x 2 segs x 2 arrays = 168 threads; pair outputs via 10-sum trick.
    // seg0: reads raw 0..47, writes 0..37. seg1: reads raw 38..83, writes 48..83
    // (same-addr read-then-write within thread; cross-seg disjoint).
    if (t < 168) {
        int arr = t & 1;
        int j2  = t >> 1;                    // 0..83
        int seg = (j2 >= 42) ? 1 : 0;
        int vr  = j2 - seg*42;
        int xb = seg ? 38 : 0;
        int nout = seg ? 18 : 19;            // pairs
        float* rA = (arr ? hP : hF) + vr*PT;
        float2 ring[5];
        float T = 0.f;
        #pragma unroll
        for (int j = 0; j < 5; ++j) {
            float2 v = *(float2*)(rA + xb + 2*j);
            ring[j] = v; T += v.x + v.y;
        }
        #pragma unroll
        for (int k2 = 0; k2 < 19; ++k2) {
            if (k2 < nout) {
                int hc = xb + 2*k2;
                float2 p = *(float2*)(rA + hc + 10);
                float2 q = ring[k2 % 5];
                float O0 = T + p.x;
                float O1 = O0 + p.y - q.x;
                T = O1 - q.y;
                ring[k2 % 5] = p;
                float2 o; o.x = O0*inv121; o.y = O1*inv121;
                *(float2*)(rA + hc + 10*seg) = o;
            }
        }
    }
    __syncthreads();

    // ---- Phase B2: a,b elementwise on pairs; float2 miv loads; in place ----
    for (int i = t; i < VR*37; i += 256) {
        int y = i / 37, c2 = i - y*37;
        int x0 = 2*c2;
        int slot = x0 + ((x0 >= 38) ? 10 : 0);
        float* pF = &hF[y*PT + slot];
        float* pP = &hP[y*PT + slot];
        float2 mp2  = *(float2*)pF;
        float2 cip2 = *(float2*)pP;
        int gy = reflect(ty0 - 5 + y);
        const float2* mrow = mivb + gy*WW;
        int gx0 = tx0 - 5 + x0;
        float2 g0 = mrow[reflect(gx0)];
        float2 g1 = mrow[reflect(gx0+1)];
        float a0 = (cip2.x - g0.x*mp2.x) * g0.y;
        float b0 = mp2.x - a0*g0.x;
        float a1 = (cip2.y - g1.x*mp2.y) * g1.y;
        float b1 = mp2.y - a1*g1.x;
        float2 oa; oa.x = a0; oa.y = a1;
        float2 ob2; ob2.x = b0; ob2.y = b1;
        *(float2*)pF = oa;
        *(float2*)pP = ob2;
    }
    __syncthreads();

    // ---- Phase C: vertical 11-sums of a,b; column-pair threads; row-slot in place ----
    // 37 pairs x 2 row-segs x 2 arrays = 148 threads.
    // seg0: reads rows 0..25, writes rows 0..15. seg1: reads 16..41, writes 26..41.
    if (t < 148) {
        int arr = t & 1;
        int j2  = t >> 1;                    // 0..73
        int seg = (j2 >= 37) ? 1 : 0;
        int c2  = j2 - seg*37;
        int x0 = 2*c2;
        int slotc = x0 + ((x0 >= 38) ? 10 : 0);
        int y0 = seg*16;
        float* A = (arr ? hP : hF);
        float2 ring[11];
        float sx = 0.f, sy = 0.f;
        #pragma unroll
        for (int j = 0; j < 10; ++j) {
            float2 v = *(float2*)(A + (y0+j)*PT + slotc);
            ring[j] = v; sx += v.x; sy += v.y;
        }
        #pragma unroll
        for (int k = 0; k < 16; ++k) {
            int y = y0 + k;
            float2 v = *(float2*)(A + (y+10)*PT + slotc);
            sx += v.x; sy += v.y;
            int wrow = y + 10*seg;
            float2 o; o.x = sx; o.y = sy;
            *(float2*)(A + wrow*PT + slotc) = o;
            sx -= ring[k%11].x; sy -= ring[k%11].y;
            ring[(k+10)%11] = v;
        }
    }
    __syncthreads();

    // ---- Phase D: horizontal 11-sums of summed a,b; pair trick; in place ----
    // 32 rows x 2 arrays x 2 col-segs = 128 threads.
    // seg0: reads slots{0..37,48..51}, writes cols 0..31. seg1: reads {32..37,48..83},
    // writes 52..83 (same-addr read-then-write; cross-seg disjoint).
    if (t < 128) {
        int arr = t & 1;
        int r2  = t >> 1;                    // 0..63
        int seg = r2 >> 5, row = r2 & 31;
        int prow = row + ((row >= 16) ? 10 : 0);
        float* rA = (arr ? hP : hF) + prow*PT;
        int xb = seg*32;
        float2 ring[5];
        float T = 0.f;
        #pragma unroll
        for (int j = 0; j < 5; ++j) {
            int idx = xb + 2*j;
            int sl = idx + ((idx >= 38) ? 10 : 0);
            float2 v = *(float2*)(rA + sl);
            ring[j] = v; T += v.x + v.y;
        }
        #pragma unroll
        for (int k2 = 0; k2 < 16; ++k2) {
            int x = xb + 2*k2;
            int idx = x + 10;
            int sl = idx + ((idx >= 38) ? 10 : 0);
            float2 p = *(float2*)(rA + sl);
            float2 q = ring[k2 % 5];
            float O0 = T + p.x;
            float O1 = O0 + p.y - q.x;
            T = O1 - q.y;
            ring[k2 % 5] = p;
            int wcol = x + 20*seg;
            float2 o; o.x = O0; o.y = O1;
            *(float2*)(rA + wcol) = o;
        }
    }
    __syncthreads();

    // ---- Phase D2: combine + coalesced float2 store ----
    float* ob = out + (size_t)bd*HW;
    for (int i = t; i < TH*32; i += 256) {
        int y = i >> 5, c2 = i & 31;
        int x0 = 2*c2;
        int prow = y + ((y >= 16) ? 10 : 0);
        int wcol = (x0 < 32) ? x0 : x0 + 20;
        float2 ma2 = *(float2*)(&hF[prow*PT + wcol]);
        float2 mb2 = *(float2*)(&hP[prow*PT + wcol]);
        int gy = ty0 + y;
        float2 im2 = *(const float2*)(ib + gy*WW + tx0 + x0);
        float2 o;
        o.x = (ma2.x*im2.x + mb2.x)*inv121;
        o.y = (ma2.y*im2.y + mb2.y)*inv121;
        *(float2*)(ob + gy*WW + tx0 + x0) = o;
    }
}

extern "C" void kernel_launch(void* const* d_in, const int* in_sizes, int n_in,
                              void* d_out, int out_size, void* d_ws, size_t ws_size,
                              hipStream_t stream) {
    const float* feat = (const float*)d_in[0];
    const float* img  = (const float*)d_in[1];
    float* out  = (float*)d_out;
    float2* miv = (float2*)d_ws;             // NB*HW float2 = 16 MiB

    img_stats<<<NB*256, 256, 0, stream>>>(img, miv);
    guided_main<<<NB*ND*128, 256, 0, stream>>>(feat, img, miv, out);
}